// Round 2
// baseline (301.105 us; speedup 1.0000x reference)
//
#include <hip/hip_runtime.h>
#include <stdint.h>

// jax_threefry_partitionable=True (default, modern JAX): 32-bit random bits
// are (out0 ^ out1) of threefry2x32(key, (hi32(i), lo32(i))). If this ever
// fails with absmax ~0.4 (independent-stream signature), flip to 0 for the
// legacy split-iota scheme.
#define THREEFRY_PARTITIONABLE 1

constexpr int BF   = 96;    // B * MAX_FRAMES
constexpr int NS   = 500;   // NUM_SAMPLES
constexpr int DSP  = 196;   // N - 1 spatial tokens
constexpr int KSEL = 49;    // TOPK
constexpr int NTOK = 197;   // N
constexpr int DIM  = 512;   // D

__device__ __forceinline__ uint32_t rotl32(uint32_t x, int r) {
  return (x << r) | (x >> (32 - r));
}

// jax threefry2x32, key = (0, 42)  (jax.random.key(42))
__device__ __forceinline__ void threefry2x32(uint32_t x0, uint32_t x1,
                                             uint32_t& o0, uint32_t& o1) {
  const uint32_t ks0 = 0u, ks1 = 42u, ks2 = 0u ^ 42u ^ 0x1BD11BDAu;
  x0 += ks0; x1 += ks1;
#define TF_R(r) { x0 += x1; x1 = rotl32(x1, (r)); x1 ^= x0; }
  TF_R(13) TF_R(15) TF_R(26) TF_R(6)   x0 += ks1; x1 += ks2 + 1u;
  TF_R(17) TF_R(29) TF_R(16) TF_R(24)  x0 += ks2; x1 += ks0 + 2u;
  TF_R(13) TF_R(15) TF_R(26) TF_R(6)   x0 += ks0; x1 += ks1 + 3u;
  TF_R(17) TF_R(29) TF_R(16) TF_R(24)  x0 += ks1; x1 += ks2 + 4u;
  TF_R(13) TF_R(15) TF_R(26) TF_R(6)   x0 += ks2; x1 += ks0 + 5u;
#undef TF_R
  o0 = x0; o1 = x1;
}

__device__ __forceinline__ uint32_t noise_bits(uint32_t p) {
#if THREEFRY_PARTITIONABLE
  // counts = iota(uint64); bind(k1, k2, hi32(i)=0, lo32(i)=i); 32-bit output
  // is out0 ^ out1 (jax _threefry_random_bits_partitionable).
  uint32_t o0, o1;
  threefry2x32(0u, p, o0, o1);
  return o0 ^ o1;
#else
  // legacy: split iota in half; first half gets out0, second half out1.
  const uint32_t half = (uint32_t)(BF * NS * DSP / 2);
  uint32_t o0, o1;
  if (p < half) { threefry2x32(p, p + half, o0, o1); return o0; }
  else          { threefry2x32(p - half, p, o0, o1); return o1; }
#endif
}

// One wave per (b, sample) row: generate 196 noise keys, select top-49
// (ties -> lower index, matching lax.top_k stability), and histogram the
// rank->index mapping into cnt[b][rank][j] (float counts, exact ints).
__global__ __launch_bounds__(256)
void topk_hist_kernel(float* __restrict__ cnt) {
  const int lane = threadIdx.x & 63;
  const int wid  = (blockIdx.x << 2) | (threadIdx.x >> 6);
  if (wid >= BF * NS) return;
  const int b = wid / NS;
  const uint32_t rowbase = (uint32_t)wid * (uint32_t)DSP;

  // Composite key: (mantissa-bits << 8) | (195 - j). Strictly distinct;
  // order = noise order (monotone bits->uniform->erfinv) with index tiebreak.
  uint32_t keys[4];
#pragma unroll
  for (int g = 0; g < 4; ++g) {
    const int j = (g << 6) | lane;
    uint32_t key = 0u;
    if (j < DSP) {
      const uint32_t bits = noise_bits(rowbase + (uint32_t)j);
      key = ((bits >> 9) << 8) | (uint32_t)(DSP - 1 - j);
    }
    keys[g] = key;
  }

  // Bitwise search for the 49th-largest key T (keys distinct => exact).
  uint32_t T = 0u;
#pragma unroll 1
  for (int bit = 30; bit >= 0; --bit) {
    const uint32_t cand = T | (1u << bit);
    const int c = __popcll(__ballot(keys[0] >= cand))
                + __popcll(__ballot(keys[1] >= cand))
                + __popcll(__ballot(keys[2] >= cand))
                + __popcll(__ballot(keys[3] >= cand));
    if (c >= KSEL) T = cand;
  }

  const uint64_t m0 = __ballot(keys[0] >= T);
  const uint64_t m1 = __ballot(keys[1] >= T);
  const uint64_t m2 = __ballot(keys[2] >= T);
  const uint64_t m3 = __ballot(keys[3] >= T);
  const int c0 = __popcll(m0);
  const int c1 = c0 + __popcll(m1);
  const int c2 = c1 + __popcll(m2);
  const uint64_t below = (1ull << lane) - 1ull;

  float* cb = cnt + (size_t)b * (KSEL * DSP);
  if ((m0 >> lane) & 1ull)
    atomicAdd(&cb[(__popcll(m0 & below)) * DSP + lane], 1.0f);
  if ((m1 >> lane) & 1ull)
    atomicAdd(&cb[(c0 + __popcll(m1 & below)) * DSP + (64 + lane)], 1.0f);
  if ((m2 >> lane) & 1ull)
    atomicAdd(&cb[(c1 + __popcll(m2 & below)) * DSP + (128 + lane)], 1.0f);
  if ((m3 >> lane) & 1ull)
    atomicAdd(&cb[(c2 + __popcll(m3 & below)) * DSP + (192 + lane)], 1.0f);
}

// out[b] = concat(cls_row, (cnt[b] @ spatial_feat[b]) / NS)
// Grid: (BF * 2) blocks; each block does 25 ranks (k-split, row 24 overlaps
// benignly with identical values). Thread = output column d.
__global__ __launch_bounds__(512)
void gather_out_kernel(const float* __restrict__ x,
                       const float* __restrict__ cnt,
                       float* __restrict__ out) {
  const int b  = blockIdx.x >> 1;
  const int ks = blockIdx.x & 1;
  const int k0 = ks * 24;           // 0..24 or 24..48
  const int d  = threadIdx.x;

  const float* xb = x + (size_t)b * NTOK * DIM;   // xf[b]
  float* ob = out + (size_t)b * (1 + KSEL) * DIM;

  if (ks == 0) ob[d] = xb[d];  // cls row

  const float* cb = cnt + (size_t)b * (KSEL * DSP) + (size_t)k0 * DSP;

  float acc[25];
#pragma unroll
  for (int k = 0; k < 25; ++k) acc[k] = 0.0f;

  for (int j0 = 0; j0 < DSP; j0 += 4) {
    float f0 = xb[(size_t)(1 + j0 + 0) * DIM + d];
    float f1 = xb[(size_t)(1 + j0 + 1) * DIM + d];
    float f2 = xb[(size_t)(1 + j0 + 2) * DIM + d];
    float f3 = xb[(size_t)(1 + j0 + 3) * DIM + d];
#pragma unroll
    for (int k = 0; k < 25; ++k) {
      const float4 c4 = *reinterpret_cast<const float4*>(cb + k * DSP + j0);
      acc[k] = fmaf(c4.x, f0, acc[k]);
      acc[k] = fmaf(c4.y, f1, acc[k]);
      acc[k] = fmaf(c4.z, f2, acc[k]);
      acc[k] = fmaf(c4.w, f3, acc[k]);
    }
  }

  const float inv = 1.0f / (float)NS;
#pragma unroll
  for (int k = 0; k < 25; ++k)
    ob[(size_t)(1 + k0 + k) * DIM + d] = acc[k] * inv;
}

extern "C" void kernel_launch(void* const* d_in, const int* in_sizes, int n_in,
                              void* d_out, int out_size, void* d_ws, size_t ws_size,
                              hipStream_t stream) {
  const float* x = (const float*)d_in[0];
  float* out = (float*)d_out;
  float* cnt = (float*)d_ws;

  const size_t cnt_bytes = (size_t)BF * KSEL * DSP * sizeof(float);
  hipMemsetAsync(cnt, 0, cnt_bytes, stream);

  topk_hist_kernel<<<dim3(BF * NS / 4), 256, 0, stream>>>(cnt);
  gather_out_kernel<<<dim3(BF * 2), 512, 0, stream>>>(x, cnt, out);
}

// Round 4
// 150.285 us; speedup vs baseline: 2.0036x; 2.0036x over previous
//
#include <hip/hip_runtime.h>
#include <stdint.h>

// jax_threefry_partitionable=True: 32-bit random bits are (out0 ^ out1) of
// threefry2x32(key, (hi32(i)=0, lo32(i)=i)), key = (0, 42).
constexpr int BF   = 96;    // B * MAX_FRAMES
constexpr int NS   = 500;   // NUM_SAMPLES
constexpr int DSP  = 196;   // N - 1 spatial tokens
constexpr int KSEL = 49;    // TOPK
constexpr int NTOK = 197;   // N
constexpr int DIM  = 512;   // D
constexpr int ROWSTRIDE = 64;  // padded byte stride of one sample's idx row

__device__ __forceinline__ uint32_t rotl32(uint32_t x, int r) {
  return (x << r) | (x >> (32 - r));
}

__device__ __forceinline__ void threefry2x32(uint32_t x0, uint32_t x1,
                                             uint32_t& o0, uint32_t& o1) {
  const uint32_t ks0 = 0u, ks1 = 42u, ks2 = 0u ^ 42u ^ 0x1BD11BDAu;
  x0 += ks0; x1 += ks1;
#define TF_R(r) { x0 += x1; x1 = rotl32(x1, (r)); x1 ^= x0; }
  TF_R(13) TF_R(15) TF_R(26) TF_R(6)   x0 += ks1; x1 += ks2 + 1u;
  TF_R(17) TF_R(29) TF_R(16) TF_R(24)  x0 += ks2; x1 += ks0 + 2u;
  TF_R(13) TF_R(15) TF_R(26) TF_R(6)   x0 += ks0; x1 += ks1 + 3u;
  TF_R(17) TF_R(29) TF_R(16) TF_R(24)  x0 += ks1; x1 += ks2 + 4u;
  TF_R(13) TF_R(15) TF_R(26) TF_R(6)   x0 += ks2; x1 += ks0 + 5u;
#undef TF_R
  o0 = x0; o1 = x1;
}

__device__ __forceinline__ uint32_t noise_bits(uint32_t p) {
  uint32_t o0, o1;
  threefry2x32(0u, p, o0, o1);
  return o0 ^ o1;
}

// One wave per (b, sample): top-49 of 196 noise keys (ties -> lower index,
// matching lax.top_k), write the 49 SORTED selected indices as bytes.
// rank = prefix popcount => consecutive set lanes write consecutive bytes.
__global__ __launch_bounds__(256)
void topk_idx_kernel(uint8_t* __restrict__ idxbuf) {
  const int lane = threadIdx.x & 63;
  const int wid  = (blockIdx.x << 2) | (threadIdx.x >> 6);
  if (wid >= BF * NS) return;
  const uint32_t rowbase = (uint32_t)wid * (uint32_t)DSP;

  // Composite key: (mantissa-bits << 8) | (195 - j). Distinct; order = noise
  // order (monotone bits->uniform->erfinv) with lower-index tiebreak.
  uint32_t keys[4];
#pragma unroll
  for (int g = 0; g < 4; ++g) {
    const int j = (g << 6) | lane;
    uint32_t key = 0u;
    if (j < DSP) {
      const uint32_t bits = noise_bits(rowbase + (uint32_t)j);
      key = ((bits >> 9) << 8) | (uint32_t)(DSP - 1 - j);
    }
    keys[g] = key;
  }

  // Bitwise search for the 49th-largest key T (keys distinct => exact).
  uint32_t T = 0u;
#pragma unroll 1
  for (int bit = 30; bit >= 0; --bit) {
    const uint32_t cand = T | (1u << bit);
    const int c = __popcll(__ballot(keys[0] >= cand))
                + __popcll(__ballot(keys[1] >= cand))
                + __popcll(__ballot(keys[2] >= cand))
                + __popcll(__ballot(keys[3] >= cand));
    if (c >= KSEL) T = cand;
  }

  const uint64_t m0 = __ballot(keys[0] >= T);
  const uint64_t m1 = __ballot(keys[1] >= T);
  const uint64_t m2 = __ballot(keys[2] >= T);
  const uint64_t m3 = __ballot(keys[3] >= T);
  const int c0 = __popcll(m0);
  const int c1 = c0 + __popcll(m1);
  const int c2 = c1 + __popcll(m2);
  const uint64_t below = (1ull << lane) - 1ull;

  uint8_t* row = idxbuf + (size_t)wid * ROWSTRIDE;
  if ((m0 >> lane) & 1ull) row[__popcll(m0 & below)]      = (uint8_t)lane;
  if ((m1 >> lane) & 1ull) row[c0 + __popcll(m1 & below)] = (uint8_t)(64 + lane);
  if ((m2 >> lane) & 1ull) row[c1 + __popcll(m2 & below)] = (uint8_t)(128 + lane);
  if ((m3 >> lane) & 1ull) row[c2 + __popcll(m3 & below)] = (uint8_t)(192 + lane);
}

// One block per (b, rank k): LDS histogram of the 500 samples' index at rank
// k, compact nonzeros, then out[b,1+k,:] = sum_j c_j * x[b,1+j,:] / NS.
// b = bid % 96 keeps all 49 blocks of one b on the same XCD (96 % 8 == 0).
__global__ __launch_bounds__(512)
void hist_gather_kernel(const float* __restrict__ x,
                        const uint8_t* __restrict__ idxbuf,
                        float* __restrict__ out) {
  const int b = blockIdx.x % BF;
  const int k = blockIdx.x / BF;
  const int d = threadIdx.x;

  __shared__ uint32_t counts[DSP];
  __shared__ uint32_t list[DSP];   // (count << 16) | j, order-independent
  __shared__ uint32_t nnz;

  if (d < DSP) counts[d] = 0u;
  if (d == 0) nnz = 0u;
  __syncthreads();

  if (d < NS) {
    const uint32_t j = idxbuf[(size_t)(b * NS + d) * ROWSTRIDE + k];
    atomicAdd(&counts[j], 1u);
  }
  __syncthreads();

  if (d < DSP) {
    const uint32_t c = counts[d];
    if (c) {
      const uint32_t p = atomicAdd(&nnz, 1u);
      list[p] = (c << 16) | (uint32_t)d;
    }
  }
  __syncthreads();

  const float* xb = x + (size_t)b * NTOK * DIM;
  const int n = (int)nnz;
  float acc = 0.0f;
#pragma unroll 4
  for (int i = 0; i < n; ++i) {
    const uint32_t e = list[i];
    acc = fmaf((float)(e >> 16), xb[(size_t)(1 + (e & 0xffffu)) * DIM + d], acc);
  }

  float* ob = out + (size_t)b * (1 + KSEL) * DIM;
  ob[(size_t)(1 + k) * DIM + d] = acc * (1.0f / (float)NS);
  if (k == 0) ob[d] = xb[d];   // cls row
}

extern "C" void kernel_launch(void* const* d_in, const int* in_sizes, int n_in,
                              void* d_out, int out_size, void* d_ws, size_t ws_size,
                              hipStream_t stream) {
  const float* x = (const float*)d_in[0];
  float* out = (float*)d_out;
  uint8_t* idxbuf = (uint8_t*)d_ws;   // BF*NS*64 = 3.07 MB

  topk_idx_kernel<<<dim3(BF * NS / 4), 256, 0, stream>>>(idxbuf);
  hist_gather_kernel<<<dim3(BF * KSEL), 512, 0, stream>>>(x, idxbuf, out);
}